// Round 1
// baseline (49921.710 us; speedup 1.0000x reference)
//
#include <hip/hip_runtime.h>
#include <cmath>

// Fused window attention w/ view-aware RoPE, fp32 baseline.
// One block per window (B=4096 blocks, 512 threads). Zero workspace.
// LDS: q/k/v head tiles + rope tables + 17KB scratch shared by
// (phaseA weight staging | softmax matrix | proj-weight transpose).

namespace {

constexpr int kN = 64;    // tokens per window
constexpr int kC = 256;   // channels
constexpr int kH = 8;     // heads
constexpr float kMaxLogit = 4.6051701859880913680f;  // log(100)
constexpr int NT = 512;

__device__ __forceinline__ float dot4(const float4 a, const float4 b) {
  return fmaf(a.x, b.x, fmaf(a.y, b.y, fmaf(a.z, b.z, a.w * b.w)));
}

__global__ __launch_bounds__(NT, 4) void fused_window_attn(
    const float* __restrict__ x, const float* __restrict__ mask,
    const float* __restrict__ qkv_w, const float* __restrict__ qkv_b,
    const float* __restrict__ proj_w, const float* __restrict__ proj_b,
    const float* __restrict__ logit_scale, float* __restrict__ out) {

  // pads chosen for 16B alignment + bank spread (see session notes)
  __shared__ float s_q[64][36];
  __shared__ float s_k[64][36];
  __shared__ float s_v[64][36];
  __shared__ float s_cs[64][16];
  __shared__ float s_sn[64][16];
  __shared__ float s_scr[64 * 68];  // union: wS[96][36]=3456 | S[64][68]=4352 | pwT[16][256]=4096

  const int b = blockIdx.x;
  const int tid = threadIdx.x;
  const int win = b & 63;  // b = g*64 + w  ->  mask window index
  const float* xb = x + (size_t)b * (kN * kC);

  const int cg = tid & 31;  // phase A: qkv dim; phase E: col quad
  const int rg = tid >> 5;  // 16 groups of 4 rows

  // ---- output accumulators (rows 4rg+i, cols {4cg+j, 128+4cg+j}), init = bias ----
  float accE[4][8];
  {
    const float4 blo = *(const float4*)(proj_b + 4 * cg);
    const float4 bhi = *(const float4*)(proj_b + 128 + 4 * cg);
#pragma unroll
    for (int i = 0; i < 4; ++i) {
      accE[i][0] = blo.x; accE[i][1] = blo.y; accE[i][2] = blo.z; accE[i][3] = blo.w;
      accE[i][4] = bhi.x; accE[i][5] = bhi.y; accE[i][6] = bhi.z; accE[i][7] = bhi.w;
    }
  }

  // ---- rope tables: angle = (n + VIEW_ID*VIEW_OFFSET) * 10000^(-i/16) ----
  for (int it = tid; it < 64 * 16; it += NT) {
    const int r = it >> 4, ii = it & 15;
    const float inv = expf(-0.575646273248511421f * (float)ii);  // log(10000)/16
    const float ang = ((float)r + 0.1f) * inv;
    s_cs[r][ii] = cosf(ang);
    s_sn[r][ii] = sinf(ang);
  }
  __syncthreads();

  const int n = tid >> 3;   // phase C/D row
  const int ms = tid & 7;   // phase C col-slot
  const int d0 = (tid & 7) * 4;  // phase D dim quad

  for (int hh = 0; hh < kH; ++hh) {
    // ================= Phase A: qkv = x @ Wqkv[head]^T =================
    float accA[4][3];
#pragma unroll
    for (int i = 0; i < 4; ++i)
#pragma unroll
      for (int j = 0; j < 3; ++j) accA[i][j] = 0.f;

    for (int kc = 0; kc < 8; ++kc) {
      __syncthreads();  // scratch reuse fence
      // stage 96 weight rows (q,k,v of this head) x 32-k chunk -> wS[96][36]
      for (int m = tid; m < 96 * 8; m += NT) {
        const int wr = m >> 3, c4 = m & 7;
        const int comp = wr >> 5, dim = wr & 31;
        const float4 wv = *(const float4*)(qkv_w + ((size_t)(comp * 256 + hh * 32 + dim) * 256 + kc * 32 + c4 * 4));
        *(float4*)(&s_scr[wr * 36 + c4 * 4]) = wv;
      }
      __syncthreads();
#pragma unroll
      for (int k4 = 0; k4 < 8; ++k4) {
        float4 xv[4];
#pragma unroll
        for (int i = 0; i < 4; ++i)
          xv[i] = *(const float4*)(xb + (4 * rg + i) * kC + kc * 32 + k4 * 4);
        float4 wv[3];
#pragma unroll
        for (int j = 0; j < 3; ++j)
          wv[j] = *(const float4*)(&s_scr[(32 * j + cg) * 36 + k4 * 4]);
#pragma unroll
        for (int i = 0; i < 4; ++i)
#pragma unroll
          for (int j = 0; j < 3; ++j) accA[i][j] += dot4(xv[i], wv[j]);
      }
    }
    // bias + park q/k/v in LDS (lanes cg -> conflict-free with pad 36? (36r+cg): cg distinct)
#pragma unroll
    for (int i = 0; i < 4; ++i) {
      s_q[4 * rg + i][cg] = accA[i][0] + qkv_b[0 * 256 + hh * 32 + cg];
      s_k[4 * rg + i][cg] = accA[i][1] + qkv_b[1 * 256 + hh * 32 + cg];
      s_v[4 * rg + i][cg] = accA[i][2] + qkv_b[2 * 256 + hh * 32 + cg];
    }
    __syncthreads();

    // ================= Phase B: RoPE (half-split) + L2 normalize =================
    for (int it = tid; it < 2048; it += NT) {
      const int buf = it >> 10;
      const int r = (it >> 4) & 63;
      const int ii = it & 15;
      float (*p)[36] = buf ? s_k : s_q;
      const float a = p[r][ii], b2 = p[r][ii + 16];
      const float c = s_cs[r][ii], s = s_sn[r][ii];
      p[r][ii] = a * c - b2 * s;
      p[r][ii + 16] = a * s + b2 * c;
    }
    __syncthreads();
    if (tid < 256) {
      const int rt = tid >> 1, half = tid & 1;
      float (*p)[36] = (rt >= 64) ? s_k : s_q;
      const int r = rt & 63;
      float ss = 0.f;
#pragma unroll
      for (int d = 16 * half; d < 16 * half + 16; ++d) ss = fmaf(p[r][d], p[r][d], ss);
      ss += __shfl_xor(ss, 1);
      const float scl = 1.0f / fmaxf(sqrtf(ss), 1e-12f);
#pragma unroll
      for (int d = 16 * half; d < 16 * half + 16; ++d) p[r][d] *= scl;
    }
    __syncthreads();

    // ================= Phase C: logits + softmax -> S in scratch =================
    const float sc_h = __expf(fminf(logit_scale[hh], kMaxLogit));
    float4 qv[8];
#pragma unroll
    for (int d4 = 0; d4 < 8; ++d4) qv[d4] = *(const float4*)(&s_q[n][d4 * 4]);
    float p8[8];
    float mx = -1e30f;
#pragma unroll
    for (int j = 0; j < 8; ++j) {
      const int m = ms + 8 * j;  // stride-8 map: k-row LDS addrs spread over banks
      float a = 0.f;
#pragma unroll
      for (int d4 = 0; d4 < 8; ++d4) a += dot4(qv[d4], *(const float4*)(&s_k[m][d4 * 4]));
      a = fmaf(a, sc_h, mask[(size_t)win * 4096 + n * 64 + m]);
      p8[j] = a;
      mx = fmaxf(mx, a);
    }
    mx = fmaxf(mx, __shfl_xor(mx, 1));
    mx = fmaxf(mx, __shfl_xor(mx, 2));
    mx = fmaxf(mx, __shfl_xor(mx, 4));
    float sm = 0.f;
#pragma unroll
    for (int j = 0; j < 8; ++j) { p8[j] = __expf(p8[j] - mx); sm += p8[j]; }
    sm += __shfl_xor(sm, 1);
    sm += __shfl_xor(sm, 2);
    sm += __shfl_xor(sm, 4);
    const float rinv = 1.0f / sm;
#pragma unroll
    for (int j = 0; j < 8; ++j) s_scr[n * 68 + ms + 8 * j] = p8[j] * rinv;
    __syncthreads();

    // ================= Phase D: attn_h = P @ V  (result -> s_q) =================
    float4 o4 = {0.f, 0.f, 0.f, 0.f};
#pragma unroll
    for (int m4 = 0; m4 < 16; ++m4) {
      const float4 pv = *(const float4*)(&s_scr[n * 68 + m4 * 4]);
      const float4 v0 = *(const float4*)(&s_v[m4 * 4 + 0][d0]);
      const float4 v1 = *(const float4*)(&s_v[m4 * 4 + 1][d0]);
      const float4 v2 = *(const float4*)(&s_v[m4 * 4 + 2][d0]);
      const float4 v3 = *(const float4*)(&s_v[m4 * 4 + 3][d0]);
      o4.x = fmaf(pv.x, v0.x, o4.x); o4.y = fmaf(pv.x, v0.y, o4.y); o4.z = fmaf(pv.x, v0.z, o4.z); o4.w = fmaf(pv.x, v0.w, o4.w);
      o4.x = fmaf(pv.y, v1.x, o4.x); o4.y = fmaf(pv.y, v1.y, o4.y); o4.z = fmaf(pv.y, v1.z, o4.z); o4.w = fmaf(pv.y, v1.w, o4.w);
      o4.x = fmaf(pv.z, v2.x, o4.x); o4.y = fmaf(pv.z, v2.y, o4.y); o4.z = fmaf(pv.z, v2.z, o4.z); o4.w = fmaf(pv.z, v2.w, o4.w);
      o4.x = fmaf(pv.w, v3.x, o4.x); o4.y = fmaf(pv.w, v3.y, o4.y); o4.z = fmaf(pv.w, v3.z, o4.z); o4.w = fmaf(pv.w, v3.w, o4.w);
    }
    *(float4*)(&s_q[n][d0]) = o4;  // s_q now holds attn_h
    __syncthreads();

    // ================= Phase E: out += attn_h @ proj_w[:, head]^T =================
    for (int dc = 0; dc < 2; ++dc) {
      __syncthreads();  // prior scratch readers done (dc=0: phase D; dc=1: previous chunk)
      for (int m = tid; m < 1024; m += NT) {
        const int c = m >> 2, dd4 = m & 3;
        const float4 v = *(const float4*)(proj_w + (size_t)c * 256 + hh * 32 + dc * 16 + dd4 * 4);
        s_scr[(dd4 * 4 + 0) * 256 + c] = v.x;
        s_scr[(dd4 * 4 + 1) * 256 + c] = v.y;
        s_scr[(dd4 * 4 + 2) * 256 + c] = v.z;
        s_scr[(dd4 * 4 + 3) * 256 + c] = v.w;
      }
      __syncthreads();
#pragma unroll
      for (int d4 = 0; d4 < 4; ++d4) {
        float4 a4[4];
#pragma unroll
        for (int i = 0; i < 4; ++i) a4[i] = *(const float4*)(&s_q[4 * rg + i][dc * 16 + d4 * 4]);
#pragma unroll
        for (int kk = 0; kk < 4; ++kk) {
          const int dd = d4 * 4 + kk;
          const float4 wlo = *(const float4*)(&s_scr[dd * 256 + 4 * cg]);
          const float4 whi = *(const float4*)(&s_scr[dd * 256 + 128 + 4 * cg]);
#pragma unroll
          for (int i = 0; i < 4; ++i) {
            const float av = (kk == 0) ? a4[i].x : (kk == 1) ? a4[i].y : (kk == 2) ? a4[i].z : a4[i].w;
            accE[i][0] = fmaf(av, wlo.x, accE[i][0]);
            accE[i][1] = fmaf(av, wlo.y, accE[i][1]);
            accE[i][2] = fmaf(av, wlo.z, accE[i][2]);
            accE[i][3] = fmaf(av, wlo.w, accE[i][3]);
            accE[i][4] = fmaf(av, whi.x, accE[i][4]);
            accE[i][5] = fmaf(av, whi.y, accE[i][5]);
            accE[i][6] = fmaf(av, whi.z, accE[i][6]);
            accE[i][7] = fmaf(av, whi.w, accE[i][7]);
          }
        }
      }
    }
    __syncthreads();  // end-of-head fence before next phase A overwrites LDS
  }

  // ---- final store (fully overwrites d_out) ----
  float* ob = out + (size_t)b * (kN * kC);
#pragma unroll
  for (int i = 0; i < 4; ++i) {
    const float4 lo = {accE[i][0], accE[i][1], accE[i][2], accE[i][3]};
    const float4 hi = {accE[i][4], accE[i][5], accE[i][6], accE[i][7]};
    *(float4*)(&ob[(4 * rg + i) * 256 + 4 * cg]) = lo;
    *(float4*)(&ob[(4 * rg + i) * 256 + 128 + 4 * cg]) = hi;
  }
}

}  // namespace

extern "C" void kernel_launch(void* const* d_in, const int* in_sizes, int n_in,
                              void* d_out, int out_size, void* d_ws, size_t ws_size,
                              hipStream_t stream) {
  (void)n_in; (void)d_ws; (void)ws_size; (void)out_size;
  const float* x = (const float*)d_in[0];
  const float* mask = (const float*)d_in[1];
  const float* qkv_w = (const float*)d_in[2];
  const float* qkv_b = (const float*)d_in[3];
  const float* proj_w = (const float*)d_in[4];
  const float* proj_b = (const float*)d_in[5];
  const float* lsc = (const float*)d_in[6];
  float* out = (float*)d_out;

  const int nB = in_sizes[0] / (kN * kC);  // 4096
  dim3 grid(nB), block(NT);
  hipLaunchKernelGGL(fused_window_attn, grid, block, 0, stream,
                     x, mask, qkv_w, qkv_b, proj_w, proj_b, lsc, out);
}